// Round 1
// baseline (590.843 us; speedup 1.0000x reference)
//
#include <hip/hip_runtime.h>
#include <math.h>

#define N_NODES 50000
#define N_EDGES 600000
#define D 128
#define NC 7
#define NP 100
#define NBLK 196   // ceil(N_NODES/256)

// ---------------- CSR build ----------------

__global__ void zero_counts_k(int* counts) {
    int i = blockIdx.x * 256 + threadIdx.x;
    if (i < N_NODES) counts[i] = 0;
}

__global__ void count_edges_k(const int* __restrict__ ei, int* __restrict__ counts) {
    int e = blockIdx.x * 256 + threadIdx.x;
    if (e < N_EDGES) atomicAdd(&counts[ei[N_EDGES + e]], 1);
}

__global__ void block_sums_k(const int* __restrict__ counts, int* __restrict__ partials) {
    __shared__ int sh[256];
    int t = threadIdx.x, b = blockIdx.x, i = b * 256 + t;
    sh[t] = (i < N_NODES) ? counts[i] : 0;
    __syncthreads();
    for (int off = 128; off > 0; off >>= 1) {
        if (t < off) sh[t] += sh[t + off];
        __syncthreads();
    }
    if (t == 0) partials[b] = sh[0];
}

__device__ inline int block_incl_scan(int v, int* sh, int t) {
    sh[t] = v;
    __syncthreads();
    for (int off = 1; off < 256; off <<= 1) {
        int add = (t >= off) ? sh[t - off] : 0;
        __syncthreads();
        sh[t] += add;
        __syncthreads();
    }
    int r = sh[t];
    __syncthreads();
    return r;
}

__global__ void scan_offsets_k(const int* __restrict__ partials, int* __restrict__ offsets) {
    __shared__ int sh[256];
    int t = threadIdx.x;
    int v = (t < NBLK) ? partials[t] : 0;
    int incl = block_incl_scan(v, sh, t);
    if (t < NBLK) offsets[t] = incl - v;   // exclusive
}

__global__ void scan_final_k(const int* __restrict__ counts, const int* __restrict__ offsets,
                             int* __restrict__ row_ptr, float* __restrict__ dinv) {
    __shared__ int sh[256];
    int t = threadIdx.x, b = blockIdx.x, i = b * 256 + t;
    int v = (i < N_NODES) ? counts[i] : 0;
    int incl = block_incl_scan(v, sh, t);
    if (i < N_NODES) {
        row_ptr[i + 1] = offsets[b] + incl;
        dinv[i] = 1.0f / sqrtf((float)(v + 1));   // +1 self loop, deg always > 0
    }
    if (i == 0) row_ptr[0] = 0;
}

__global__ void init_cursor_k(const int* __restrict__ row_ptr, int* __restrict__ cursor) {
    int i = blockIdx.x * 256 + threadIdx.x;
    if (i < N_NODES) cursor[i] = row_ptr[i];
}

__global__ void fill_csr_k(const int* __restrict__ ei, int* __restrict__ cursor,
                           int* __restrict__ csr_src) {
    int e = blockIdx.x * 256 + threadIdx.x;
    if (e >= N_EDGES) return;
    int s = ei[e], d = ei[N_EDGES + e];
    int pos = atomicAdd(&cursor[d], 1);
    csr_src[pos] = s;
}

// ---------------- dense GEMM: out[N,128] = in[N,128] @ W[128,128] ----------------

__global__ __launch_bounds__(256) void gemm128_k(const float* __restrict__ in,
                                                 const float* __restrict__ W,
                                                 float* __restrict__ out) {
    __shared__ float Wl[128 * 128];
    int t = threadIdx.x;
    for (int i = t * 4; i < 128 * 128; i += 1024)
        *(float4*)&Wl[i] = *(const float4*)&W[i];
    __syncthreads();
    int c4 = (t & 31) * 4;
    int rh = t >> 5;               // 0..7
    int r0 = blockIdx.x * 32;
    for (int ri = 0; ri < 4; ri++) {
        int r = r0 + rh + ri * 8;
        if (r >= N_NODES) break;
        const float* hrow = &in[(size_t)r * 128];
        float4 acc = {0.f, 0.f, 0.f, 0.f};
        #pragma unroll 8
        for (int k0 = 0; k0 < 128; k0 += 4) {
            float4 hv = *(const float4*)&hrow[k0];
            float4 w0 = *(const float4*)&Wl[(k0 + 0) * 128 + c4];
            float4 w1 = *(const float4*)&Wl[(k0 + 1) * 128 + c4];
            float4 w2 = *(const float4*)&Wl[(k0 + 2) * 128 + c4];
            float4 w3 = *(const float4*)&Wl[(k0 + 3) * 128 + c4];
            acc.x += hv.x * w0.x + hv.y * w1.x + hv.z * w2.x + hv.w * w3.x;
            acc.y += hv.x * w0.y + hv.y * w1.y + hv.z * w2.y + hv.w * w3.y;
            acc.z += hv.x * w0.z + hv.y * w1.z + hv.z * w2.z + hv.w * w3.z;
            acc.w += hv.x * w0.w + hv.y * w1.w + hv.z * w2.w + hv.w * w3.w;
        }
        *(float4*)&out[(size_t)r * 128 + c4] = acc;
    }
}

// ---------------- aggregation: one wave per node, CSR gather ----------------

__global__ __launch_bounds__(256) void aggregate_k(const float* __restrict__ hw,
                                                   const int* __restrict__ row_ptr,
                                                   const int* __restrict__ csr_src,
                                                   const float* __restrict__ dinv,
                                                   const float* __restrict__ bias,
                                                   float* __restrict__ out, int relu) {
    int wid = (blockIdx.x * 256 + threadIdx.x) >> 6;
    int lane = threadIdx.x & 63;
    if (wid >= N_NODES) return;
    float di = dinv[wid];
    float2 hv = *(const float2*)&hw[(size_t)wid * 128 + lane * 2];
    float ax = hv.x * di * di, ay = hv.y * di * di;   // self loop
    int e = row_ptr[wid], end = row_ptr[wid + 1];
    for (; e < end; ++e) {
        int s = csr_src[e];
        float w = dinv[s] * di;
        float2 v = *(const float2*)&hw[(size_t)s * 128 + lane * 2];
        ax += v.x * w;
        ay += v.y * w;
    }
    float2 bb = *(const float2*)&bias[lane * 2];
    ax += bb.x;
    ay += bb.y;
    if (relu) { ax = fmaxf(ax, 0.f); ay = fmaxf(ay, 0.f); }
    float2 r = {ax, ay};
    *(float2*)&out[(size_t)wid * 128 + lane * 2] = r;
}

// ---------------- row L2 normalize ----------------

__global__ __launch_bounds__(256) void normalize_k(const float* __restrict__ in,
                                                   float* __restrict__ out) {
    int wid = (blockIdx.x * 256 + threadIdx.x) >> 6;
    int lane = threadIdx.x & 63;
    if (wid >= N_NODES) return;
    float2 v = *(const float2*)&in[(size_t)wid * 128 + lane * 2];
    float ss = v.x * v.x + v.y * v.y;
    for (int o = 32; o > 0; o >>= 1) ss += __shfl_xor(ss, o);
    float inv = 1.0f / sqrtf(ss);
    float2 r = {v.x * inv, v.y * inv};
    *(float2*)&out[(size_t)wid * 128 + lane * 2] = r;
}

// ---------------- prototype head: out_proto[100,7] log-probs ----------------

__global__ __launch_bounds__(128) void proto_head_k(const float* __restrict__ hn,
                                                    const int* __restrict__ prot,
                                                    const float* __restrict__ lw1,
                                                    const float* __restrict__ lb1,
                                                    const float* __restrict__ lw2,
                                                    const float* __restrict__ lb2,
                                                    float* __restrict__ out_proto) {
    __shared__ float a[128];
    __shared__ float hid[128];
    __shared__ float lg[7];
    __shared__ float lse_s;
    int p = blockIdx.x, t = threadIdx.x;
    int node = prot[p];
    a[t] = hn[(size_t)node * 128 + t];
    __syncthreads();
    float acc = lb1[t];
    for (int k = 0; k < 128; k++) acc += a[k] * lw1[k * 128 + t];
    hid[t] = fmaxf(acc, 0.f);
    __syncthreads();
    if (t < NC) {
        float l = lb2[t];
        for (int k = 0; k < 128; k++) l += hid[k] * lw2[k * NC + t];
        lg[t] = l;
    }
    __syncthreads();
    if (t == 0) {
        float m = lg[0];
        for (int c = 1; c < NC; c++) m = fmaxf(m, lg[c]);
        float s = 0.f;
        for (int c = 0; c < NC; c++) s += expf(lg[c] - m);
        lse_s = m + logf(s);
    }
    __syncthreads();
    if (t < NC) out_proto[p * NC + t] = lg[t] - lse_s;
}

// ---------------- fused relative-rep + classifier head ----------------

__global__ __launch_bounds__(256) void rel_out_k(const float* __restrict__ hn,
                                                 const int* __restrict__ prot,
                                                 const float* __restrict__ op,
                                                 float* __restrict__ x_rel,
                                                 float* __restrict__ out) {
    __shared__ float A[NP * 128];   // 51.2 KB anchors
    __shared__ float OP[NP * 8];    // padded out_proto
    int t = threadIdx.x;
    for (int i = t; i < NP * 128; i += 256) {
        int p = i >> 7, k = i & 127;
        A[i] = hn[(size_t)prot[p] * 128 + k];
    }
    for (int i = t; i < NP * NC; i += 256) OP[(i / NC) * 8 + (i % NC)] = op[i];
    __syncthreads();
    int node = blockIdx.x * 256 + t;
    if (node >= N_NODES) return;
    float4 h[32];
    const float* hp = &hn[(size_t)node * 128];
    #pragma unroll
    for (int k = 0; k < 32; k++) h[k] = *(const float4*)&hp[k * 4];
    float lg[NC] = {0, 0, 0, 0, 0, 0, 0};
    float* xr_row = &x_rel[(size_t)node * NP];
    for (int p = 0; p < NP; ++p) {
        const float* Ap = &A[p * 128];
        float a0 = 0, a1 = 0, a2 = 0, a3 = 0;
        #pragma unroll
        for (int k = 0; k < 32; k++) {
            float4 av = *(const float4*)&Ap[k * 4];
            a0 += h[k].x * av.x;
            a1 += h[k].y * av.y;
            a2 += h[k].z * av.z;
            a3 += h[k].w * av.w;
        }
        float xr = ((a0 + a1) + (a2 + a3) + 1.0f) * 0.5f;
        xr_row[p] = xr;
        #pragma unroll
        for (int c = 0; c < NC; c++) lg[c] += xr * OP[p * 8 + c];
    }
    float m = lg[0];
    #pragma unroll
    for (int c = 1; c < NC; c++) m = fmaxf(m, lg[c]);
    float s = 0.f;
    #pragma unroll
    for (int c = 0; c < NC; c++) s += expf(lg[c] - m);
    float lse = m + logf(s);
    #pragma unroll
    for (int c = 0; c < NC; c++) out[(size_t)node * NC + c] = lg[c] - lse;
}

// ---------------- launch ----------------

extern "C" void kernel_launch(void* const* d_in, const int* in_sizes, int n_in,
                              void* d_out, int out_size, void* d_ws, size_t ws_size,
                              hipStream_t stream) {
    const float* x   = (const float*)d_in[0];
    const int*   ei  = (const int*)d_in[1];
    const int*   prot= (const int*)d_in[2];
    const float* W0  = (const float*)d_in[3];
    const float* b0  = (const float*)d_in[4];
    const float* W1  = (const float*)d_in[5];
    const float* b1  = (const float*)d_in[6];
    const float* W2  = (const float*)d_in[7];
    const float* b2  = (const float*)d_in[8];
    const float* lw1 = (const float*)d_in[9];
    const float* lb1 = (const float*)d_in[10];
    const float* lw2 = (const float*)d_in[11];
    const float* lb2 = (const float*)d_in[12];

    float* out       = (float*)d_out;             // [N,7]
    float* x_rel     = out + (size_t)N_NODES * NC;           // [N,100]
    float* out_proto = out + (size_t)N_NODES * NC + (size_t)N_NODES * NP; // [100,7]

    // workspace layout (element offsets)
    int* wi = (int*)d_ws;
    int* counts   = wi;             // 50000
    int* row_ptr  = wi + 50048;     // 50001
    int* cursor   = wi + 100096;    // 50000
    int* partials = wi + 150144;    // 256
    int* offsets  = wi + 150464;    // 256
    int* csr_src  = wi + 150784;    // 600000 -> ends 750784
    float* wf = (float*)d_ws;
    float* dinv = wf + 750848;      // 50000
    float* bufA = wf + 800896;      // 6.4M
    float* bufB = wf + 7200896;     // 6.4M
    float* bufC = wf + 13600896;    // 6.4M -> ends 20,000,896 floats (~80 MB)

    const int egrid = (N_EDGES + 255) / 256;  // 2344
    const int ggrid = (N_NODES + 31) / 32;    // 1563
    const int wgrid = (N_NODES * 64) / 256;   // 12500 (one wave per node)

    // CSR build + degrees
    hipLaunchKernelGGL(zero_counts_k, dim3(NBLK), dim3(256), 0, stream, counts);
    hipLaunchKernelGGL(count_edges_k, dim3(egrid), dim3(256), 0, stream, ei, counts);
    hipLaunchKernelGGL(block_sums_k, dim3(NBLK), dim3(256), 0, stream, counts, partials);
    hipLaunchKernelGGL(scan_offsets_k, dim3(1), dim3(256), 0, stream, partials, offsets);
    hipLaunchKernelGGL(scan_final_k, dim3(NBLK), dim3(256), 0, stream, counts, offsets, row_ptr, dinv);
    hipLaunchKernelGGL(init_cursor_k, dim3(NBLK), dim3(256), 0, stream, row_ptr, cursor);
    hipLaunchKernelGGL(fill_csr_k, dim3(egrid), dim3(256), 0, stream, ei, cursor, csr_src);

    // conv0: x @ W0 -> bufA ; aggregate -> bufB (relu)
    hipLaunchKernelGGL(gemm128_k, dim3(ggrid), dim3(256), 0, stream, x, W0, bufA);
    hipLaunchKernelGGL(aggregate_k, dim3(wgrid), dim3(256), 0, stream, bufA, row_ptr, csr_src, dinv, b0, bufB, 1);
    // conv1: bufB @ W1 -> bufA ; aggregate -> bufC (relu)
    hipLaunchKernelGGL(gemm128_k, dim3(ggrid), dim3(256), 0, stream, bufB, W1, bufA);
    hipLaunchKernelGGL(aggregate_k, dim3(wgrid), dim3(256), 0, stream, bufA, row_ptr, csr_src, dinv, b1, bufC, 1);
    // conv2: bufC @ W2 -> bufA ; aggregate -> bufB (no relu)
    hipLaunchKernelGGL(gemm128_k, dim3(ggrid), dim3(256), 0, stream, bufC, W2, bufA);
    hipLaunchKernelGGL(aggregate_k, dim3(wgrid), dim3(256), 0, stream, bufA, row_ptr, csr_src, dinv, b2, bufB, 0);

    // normalize -> bufC (= hn)
    hipLaunchKernelGGL(normalize_k, dim3(wgrid), dim3(256), 0, stream, bufB, bufC);

    // prototype head -> out_proto (in d_out)
    hipLaunchKernelGGL(proto_head_k, dim3(NP), dim3(128), 0, stream, bufC, prot, lw1, lb1, lw2, lb2, out_proto);

    // fused relative representation + log_softmax head
    hipLaunchKernelGGL(rel_out_k, dim3(NBLK), dim3(256), 0, stream, bufC, prot, out_proto, x_rel, out);
}

// Round 2
// 374.526 us; speedup vs baseline: 1.5776x; 1.5776x over previous
//
#include <hip/hip_runtime.h>
#include <math.h>

#define N_NODES 50000
#define N_EDGES 600000
#define NPAD 50048          // 391 * 128
#define D 128
#define NC 7
#define NP 100
#define NBLK 196            // ceil(N_NODES/256)
#define GBLK 391            // NPAD / 128

typedef unsigned short u16;
typedef unsigned int u32;
typedef __attribute__((ext_vector_type(8))) short bf16x8;
typedef __attribute__((ext_vector_type(4))) float f32x4;

__device__ inline u16 bf16rn(float f) {
    u32 u = __float_as_uint(f);
    u32 r = (u + 0x7fffu + ((u >> 16) & 1u)) >> 16;
    return (u16)r;
}
__device__ inline float bflo(u32 u) { return __uint_as_float(u << 16); }
__device__ inline float bfhi(u32 u) { return __uint_as_float(u & 0xffff0000u); }

// ---------------- CSR build ----------------

__global__ void zero_counts_k(int* counts) {
    int i = blockIdx.x * 256 + threadIdx.x;
    if (i < N_NODES) counts[i] = 0;
}

__global__ void count_edges_k(const int* __restrict__ ei, int* __restrict__ counts) {
    int e = blockIdx.x * 256 + threadIdx.x;
    if (e < N_EDGES) atomicAdd(&counts[ei[N_EDGES + e]], 1);
}

__global__ void block_sums_k(const int* __restrict__ counts, int* __restrict__ partials) {
    __shared__ int sh[256];
    int t = threadIdx.x, b = blockIdx.x, i = b * 256 + t;
    sh[t] = (i < N_NODES) ? counts[i] : 0;
    __syncthreads();
    for (int off = 128; off > 0; off >>= 1) {
        if (t < off) sh[t] += sh[t + off];
        __syncthreads();
    }
    if (t == 0) partials[b] = sh[0];
}

__device__ inline int block_incl_scan(int v, int* sh, int t) {
    sh[t] = v;
    __syncthreads();
    for (int off = 1; off < 256; off <<= 1) {
        int add = (t >= off) ? sh[t - off] : 0;
        __syncthreads();
        sh[t] += add;
        __syncthreads();
    }
    int r = sh[t];
    __syncthreads();
    return r;
}

__global__ void scan_offsets_k(const int* __restrict__ partials, int* __restrict__ offsets) {
    __shared__ int sh[256];
    int t = threadIdx.x;
    int v = (t < NBLK) ? partials[t] : 0;
    int incl = block_incl_scan(v, sh, t);
    if (t < NBLK) offsets[t] = incl - v;   // exclusive
}

__global__ void scan_final_k(const int* __restrict__ counts, const int* __restrict__ offsets,
                             int* __restrict__ row_ptr, float* __restrict__ dinv) {
    __shared__ int sh[256];
    int t = threadIdx.x, b = blockIdx.x, i = b * 256 + t;
    int v = (i < N_NODES) ? counts[i] : 0;
    int incl = block_incl_scan(v, sh, t);
    if (i < N_NODES) {
        row_ptr[i + 1] = offsets[b] + incl;
        dinv[i] = 1.0f / sqrtf((float)(v + 1));
    }
    if (i == 0) row_ptr[0] = 0;
}

__global__ void init_cursor_k(const int* __restrict__ row_ptr, int* __restrict__ cursor) {
    int i = blockIdx.x * 256 + threadIdx.x;
    if (i < N_NODES) cursor[i] = row_ptr[i];
}

__global__ void fill_csr_k(const int* __restrict__ ei, int* __restrict__ cursor,
                           int* __restrict__ csr_src) {
    int e = blockIdx.x * 256 + threadIdx.x;
    if (e >= N_EDGES) return;
    int s = ei[e], d = ei[N_EDGES + e];
    int pos = atomicAdd(&cursor[d], 1);
    csr_src[pos] = s;
}

// ---------------- cast f32 -> bf16 ----------------

__global__ void cast_f2b_k(const float* __restrict__ src, u16* __restrict__ dst, int n4) {
    int i = blockIdx.x * 256 + threadIdx.x;
    if (i >= n4) return;
    float4 v = *(const float4*)&src[i * 4];
    u32 lo = (u32)bf16rn(v.x) | ((u32)bf16rn(v.y) << 16);
    u32 hi = (u32)bf16rn(v.z) | ((u32)bf16rn(v.w) << 16);
    uint2 o = {lo, hi};
    *(uint2*)&dst[i * 4] = o;
}

// ---------------- MFMA GEMM: out[NPAD,128](bf16) = in[NPAD,128](bf16) @ W[128,128](f32) ----
// block = 256 thr (4 waves), tile 128 rows x 128 cols; wave: 32 rows x 128 cols.

__global__ __launch_bounds__(256) void gemm_mfma_k(const u16* __restrict__ in,
                                                   const float* __restrict__ W,
                                                   u16* __restrict__ out) {
    __shared__ u16 Wt[128 * 128];   // Wt[col][k] bf16, byte ^= (col&7)<<4
    int t = threadIdx.x;
    for (int i = t * 4; i < 128 * 128; i += 1024) {
        float4 w4 = *(const float4*)&W[i];
        int k = i >> 7, c0 = i & 127;
        u16 vals[4] = {bf16rn(w4.x), bf16rn(w4.y), bf16rn(w4.z), bf16rn(w4.w)};
        #pragma unroll
        for (int j = 0; j < 4; j++) {
            int col = c0 + j;
            int byte = (col << 8) | (((k << 1)) ^ ((col & 7) << 4));
            *(u16*)((char*)Wt + byte) = vals[j];
        }
    }
    __syncthreads();
    int w = t >> 6, lane = t & 63;
    int arow = lane & 15, kg = lane >> 4;
    int r0 = blockIdx.x * 128 + w * 32;

    bf16x8 a[2][4];
    #pragma unroll
    for (int rt = 0; rt < 2; rt++)
        #pragma unroll
        for (int ks = 0; ks < 4; ks++)
            a[rt][ks] = *(const bf16x8*)&in[(size_t)(r0 + rt * 16 + arow) * 128 + ks * 32 + kg * 8];

    f32x4 acc[2][8];
    #pragma unroll
    for (int rt = 0; rt < 2; rt++)
        #pragma unroll
        for (int ct = 0; ct < 8; ct++) acc[rt][ct] = (f32x4){0.f, 0.f, 0.f, 0.f};

    #pragma unroll
    for (int ct = 0; ct < 8; ct++) {
        int col = ct * 16 + arow;
        int cbase = col << 8, swz = (col & 7) << 4;
        #pragma unroll
        for (int ks = 0; ks < 4; ks++) {
            int kb2 = (ks * 32 + kg * 8) << 1;
            bf16x8 b = *(const bf16x8*)((const char*)Wt + (cbase | (kb2 ^ swz)));
            acc[0][ct] = __builtin_amdgcn_mfma_f32_16x16x32_bf16(a[0][ks], b, acc[0][ct], 0, 0, 0);
            acc[1][ct] = __builtin_amdgcn_mfma_f32_16x16x32_bf16(a[1][ks], b, acc[1][ct], 0, 0, 0);
        }
    }
    #pragma unroll
    for (int rt = 0; rt < 2; rt++) {
        #pragma unroll
        for (int ct = 0; ct < 8; ct++) {
            int col = ct * 16 + arow;
            #pragma unroll
            for (int j = 0; j < 4; j++) {
                int row = r0 + rt * 16 + kg * 4 + j;
                if (row < N_NODES) out[(size_t)row * 128 + col] = bf16rn(acc[rt][ct][j]);
            }
        }
    }
}

// ---------------- aggregation: one wave per node, CSR gather over bf16 features -------

template<int RELU, int OUTBF>
__global__ __launch_bounds__(256) void aggregate_k(const u16* __restrict__ hwb,
                                                   const int* __restrict__ row_ptr,
                                                   const int* __restrict__ csr_src,
                                                   const float* __restrict__ dinv,
                                                   const float* __restrict__ bias,
                                                   void* __restrict__ outv) {
    int wid = (blockIdx.x * 256 + threadIdx.x) >> 6;
    int lane = threadIdx.x & 63;
    if (wid >= N_NODES) return;
    float di = dinv[wid];
    u32 u = *(const u32*)&hwb[(size_t)wid * 128 + lane * 2];
    float ax = bflo(u) * di * di, ay = bfhi(u) * di * di;   // self loop
    int e = row_ptr[wid], end = row_ptr[wid + 1];
    for (; e < end; ++e) {
        int s = csr_src[e];
        float w = dinv[s] * di;
        u32 v = *(const u32*)&hwb[(size_t)s * 128 + lane * 2];
        ax += bflo(v) * w;
        ay += bfhi(v) * w;
    }
    float2 bb = *(const float2*)&bias[lane * 2];
    ax += bb.x;
    ay += bb.y;
    if (RELU) { ax = fmaxf(ax, 0.f); ay = fmaxf(ay, 0.f); }
    if (OUTBF) {
        u32 o = (u32)bf16rn(ax) | ((u32)bf16rn(ay) << 16);
        *(u32*)&((u16*)outv)[(size_t)wid * 128 + lane * 2] = o;
    } else {
        float2 r = {ax, ay};
        *(float2*)&((float*)outv)[(size_t)wid * 128 + lane * 2] = r;
    }
}

// ---------------- row L2 normalize (in-place f32) + bf16 copy ----------------

__global__ __launch_bounds__(256) void normalize_k(float* __restrict__ h, u16* __restrict__ hnb) {
    int wid = (blockIdx.x * 256 + threadIdx.x) >> 6;
    int lane = threadIdx.x & 63;
    if (wid >= N_NODES) return;
    float2 v = *(const float2*)&h[(size_t)wid * 128 + lane * 2];
    float ss = v.x * v.x + v.y * v.y;
    for (int o = 32; o > 0; o >>= 1) ss += __shfl_xor(ss, o);
    float inv = 1.0f / sqrtf(ss);
    v.x *= inv; v.y *= inv;
    *(float2*)&h[(size_t)wid * 128 + lane * 2] = v;
    u32 o = (u32)bf16rn(v.x) | ((u32)bf16rn(v.y) << 16);
    *(u32*)&hnb[(size_t)wid * 128 + lane * 2] = o;
}

// ---------------- prototype head: out_proto[100,7] log-probs (f32 path) ----------------

__global__ __launch_bounds__(128) void proto_head_k(const float* __restrict__ hn,
                                                    const int* __restrict__ prot,
                                                    const float* __restrict__ lw1,
                                                    const float* __restrict__ lb1,
                                                    const float* __restrict__ lw2,
                                                    const float* __restrict__ lb2,
                                                    float* __restrict__ out_proto) {
    __shared__ float a[128];
    __shared__ float hid[128];
    __shared__ float lg[7];
    __shared__ float lse_s;
    int p = blockIdx.x, t = threadIdx.x;
    int node = prot[p];
    a[t] = hn[(size_t)node * 128 + t];
    __syncthreads();
    float acc = lb1[t];
    for (int k = 0; k < 128; k++) acc += a[k] * lw1[k * 128 + t];
    hid[t] = fmaxf(acc, 0.f);
    __syncthreads();
    if (t < NC) {
        float l = lb2[t];
        for (int k = 0; k < 128; k++) l += hid[k] * lw2[k * NC + t];
        lg[t] = l;
    }
    __syncthreads();
    if (t == 0) {
        float m = lg[0];
        for (int c = 1; c < NC; c++) m = fmaxf(m, lg[c]);
        float s = 0.f;
        for (int c = 0; c < NC; c++) s += expf(lg[c] - m);
        lse_s = m + logf(s);
    }
    __syncthreads();
    if (t < NC) out_proto[p * NC + t] = lg[t] - lse_s;
}

// ---------------- fused MFMA rel-rep + classifier head ----------------
// block: 256 thr (4 waves), 128 rows; cols = 112 (100 anchors padded).

__global__ __launch_bounds__(256) void rel_out_k(const u16* __restrict__ hnb,
                                                 const int* __restrict__ prot,
                                                 const float* __restrict__ op,
                                                 float* __restrict__ x_rel,
                                                 float* __restrict__ out) {
    __shared__ u16 Asw[112 * 128];   // anchors[p][k] bf16, byte ^= (p&7)<<4 ; 28672 B
    __shared__ float OPl[112 * 9];   // out_proto padded [112][9] ; 4032 B
    int t = threadIdx.x;
    for (int i = t * 4; i < 112 * 128; i += 1024) {
        int p = i >> 7, k = i & 127;
        uint2 d = {0u, 0u};
        if (p < NP) d = *(const uint2*)&hnb[(size_t)prot[p] * 128 + k];
        int byte = (p << 8) | (((k << 1)) ^ ((p & 7) << 4));
        *(uint2*)((char*)Asw + byte) = d;
    }
    for (int i = t; i < 112 * 9; i += 256) {
        int p = i / 9, c = i % 9;
        OPl[i] = (p < NP && c < NC) ? op[p * NC + c] : 0.f;
    }
    __syncthreads();

    int w = t >> 6, lane = t & 63;
    int arow = lane & 15, kg = lane >> 4;
    int r0 = blockIdx.x * 128 + w * 32;

    bf16x8 a[2][4];
    #pragma unroll
    for (int rt = 0; rt < 2; rt++)
        #pragma unroll
        for (int ks = 0; ks < 4; ks++)
            a[rt][ks] = *(const bf16x8*)&hnb[(size_t)(r0 + rt * 16 + arow) * 128 + ks * 32 + kg * 8];

    f32x4 acc[2][7];
    #pragma unroll
    for (int rt = 0; rt < 2; rt++)
        #pragma unroll
        for (int ct = 0; ct < 7; ct++) acc[rt][ct] = (f32x4){0.f, 0.f, 0.f, 0.f};

    #pragma unroll
    for (int ct = 0; ct < 7; ct++) {
        int col = ct * 16 + arow;
        int cbase = col << 8, swz = (col & 7) << 4;
        #pragma unroll
        for (int ks = 0; ks < 4; ks++) {
            int kb2 = (ks * 32 + kg * 8) << 1;
            bf16x8 b = *(const bf16x8*)((const char*)Asw + (cbase | (kb2 ^ swz)));
            acc[0][ct] = __builtin_amdgcn_mfma_f32_16x16x32_bf16(a[0][ks], b, acc[0][ct], 0, 0, 0);
            acc[1][ct] = __builtin_amdgcn_mfma_f32_16x16x32_bf16(a[1][ks], b, acc[1][ct], 0, 0, 0);
        }
    }

    // epilogue: x_rel store + lg = xr @ OP, 16-lane reduce, log_softmax
    #pragma unroll
    for (int rt = 0; rt < 2; rt++) {
        #pragma unroll
        for (int j = 0; j < 4; j++) {
            int row = r0 + rt * 16 + kg * 4 + j;
            float lg[7] = {0.f, 0.f, 0.f, 0.f, 0.f, 0.f, 0.f};
            #pragma unroll
            for (int ct = 0; ct < 7; ct++) {
                int p = ct * 16 + arow;
                float xr = (acc[rt][ct][j] + 1.0f) * 0.5f;
                if (row < N_NODES && p < NP) x_rel[(size_t)row * NP + p] = xr;
                #pragma unroll
                for (int c = 0; c < NC; c++) lg[c] += xr * OPl[p * 9 + c];
            }
            #pragma unroll
            for (int m = 1; m < 16; m <<= 1) {
                #pragma unroll
                for (int c = 0; c < NC; c++) lg[c] += __shfl_xor(lg[c], m);
            }
            float mx = lg[0];
            #pragma unroll
            for (int c = 1; c < NC; c++) mx = fmaxf(mx, lg[c]);
            float s = 0.f;
            #pragma unroll
            for (int c = 0; c < NC; c++) s += expf(lg[c] - mx);
            float lse = mx + logf(s);
            if (arow == 0 && row < N_NODES) {
                #pragma unroll
                for (int c = 0; c < NC; c++) out[(size_t)row * NC + c] = lg[c] - lse;
            }
        }
    }
}

// ---------------- launch ----------------

extern "C" void kernel_launch(void* const* d_in, const int* in_sizes, int n_in,
                              void* d_out, int out_size, void* d_ws, size_t ws_size,
                              hipStream_t stream) {
    const float* x   = (const float*)d_in[0];
    const int*   ei  = (const int*)d_in[1];
    const int*   prot= (const int*)d_in[2];
    const float* W0  = (const float*)d_in[3];
    const float* b0  = (const float*)d_in[4];
    const float* W1  = (const float*)d_in[5];
    const float* b1  = (const float*)d_in[6];
    const float* W2  = (const float*)d_in[7];
    const float* b2  = (const float*)d_in[8];
    const float* lw1 = (const float*)d_in[9];
    const float* lb1 = (const float*)d_in[10];
    const float* lw2 = (const float*)d_in[11];
    const float* lb2 = (const float*)d_in[12];

    float* out       = (float*)d_out;                                      // [N,7]
    float* x_rel     = out + (size_t)N_NODES * NC;                         // [N,100]
    float* out_proto = out + (size_t)N_NODES * NC + (size_t)N_NODES * NP;  // [100,7]

    // workspace layout
    int* wi = (int*)d_ws;
    int* counts   = wi;             // 50000
    int* row_ptr  = wi + 50048;     // 50001
    int* cursor   = wi + 100096;    // 50000
    int* partials = wi + 150144;    // 256
    int* offsets  = wi + 150464;    // 256
    int* csr_src  = wi + 150784;    // 600000 -> ends 750784
    float* wf = (float*)d_ws;
    float* dinv = wf + 750848;      // 50000 -> 800848, round to 800896
    float* bufF = wf + 800896;      // 6.4M f32 (agg L2 out, then hn in-place) -> ends 7200896
    char* cb = (char*)d_ws;
    u16* xb  = (u16*)(cb + (size_t)7200896 * 4);                       // NPAD*128 bf16 = 12.8MB
    u16* hwb = (u16*)(cb + (size_t)7200896 * 4 + (size_t)NPAD * 256);  // 12.8MB
    u16* hb  = (u16*)(cb + (size_t)7200896 * 4 + (size_t)NPAD * 512);  // 12.8MB

    const int egrid = (N_EDGES + 255) / 256;  // 2344
    const int wgrid = (N_NODES * 64) / 256;   // 12500
    const int cgrid = (N_NODES * 128 / 4 + 255) / 256;  // 6250

    // CSR build + degrees
    hipLaunchKernelGGL(zero_counts_k, dim3(NBLK), dim3(256), 0, stream, counts);
    hipLaunchKernelGGL(count_edges_k, dim3(egrid), dim3(256), 0, stream, ei, counts);
    hipLaunchKernelGGL(block_sums_k, dim3(NBLK), dim3(256), 0, stream, counts, partials);
    hipLaunchKernelGGL(scan_offsets_k, dim3(1), dim3(256), 0, stream, partials, offsets);
    hipLaunchKernelGGL(scan_final_k, dim3(NBLK), dim3(256), 0, stream, counts, offsets, row_ptr, dinv);
    hipLaunchKernelGGL(init_cursor_k, dim3(NBLK), dim3(256), 0, stream, row_ptr, cursor);
    hipLaunchKernelGGL(fill_csr_k, dim3(egrid), dim3(256), 0, stream, ei, cursor, csr_src);

    // cast x -> bf16
    hipLaunchKernelGGL(cast_f2b_k, dim3(cgrid), dim3(256), 0, stream, x, xb, N_NODES * 32);

    // conv0
    hipLaunchKernelGGL(gemm_mfma_k, dim3(GBLK), dim3(256), 0, stream, xb, W0, hwb);
    hipLaunchKernelGGL((aggregate_k<1, 1>), dim3(wgrid), dim3(256), 0, stream, hwb, row_ptr, csr_src, dinv, b0, (void*)hb);
    // conv1
    hipLaunchKernelGGL(gemm_mfma_k, dim3(GBLK), dim3(256), 0, stream, hb, W1, hwb);
    hipLaunchKernelGGL((aggregate_k<1, 1>), dim3(wgrid), dim3(256), 0, stream, hwb, row_ptr, csr_src, dinv, b1, (void*)xb);
    // conv2 (no relu, f32 out)
    hipLaunchKernelGGL(gemm_mfma_k, dim3(GBLK), dim3(256), 0, stream, xb, W2, hwb);
    hipLaunchKernelGGL((aggregate_k<0, 0>), dim3(wgrid), dim3(256), 0, stream, hwb, row_ptr, csr_src, dinv, b2, (void*)bufF);

    // normalize in-place (f32) + bf16 copy -> hb
    hipLaunchKernelGGL(normalize_k, dim3(wgrid), dim3(256), 0, stream, bufF, hb);

    // prototype head (f32 anchors) -> out_proto
    hipLaunchKernelGGL(proto_head_k, dim3(NP), dim3(128), 0, stream, bufF, prot, lw1, lb1, lw2, lb2, out_proto);

    // fused MFMA relative representation + classifier + log_softmax
    hipLaunchKernelGGL(rel_out_k, dim3(GBLK), dim3(256), 0, stream, hb, prot, out_proto, x_rel, out);
}

// Round 3
// 268.049 us; speedup vs baseline: 2.2042x; 1.3972x over previous
//
#include <hip/hip_runtime.h>
#include <math.h>

#define N_NODES 50000
#define N_EDGES 600000
#define NPAD 50048          // 391 * 128
#define D 128
#define NC 7
#define NP 100
#define NBLK 196            // ceil(N_NODES/256)
#define GBLK 391            // NPAD / 128

typedef unsigned short u16;
typedef unsigned int u32;
typedef __attribute__((ext_vector_type(8))) short bf16x8;
typedef __attribute__((ext_vector_type(4))) float f32x4;

__device__ inline u16 bf16rn(float f) {
    u32 u = __float_as_uint(f);
    u32 r = (u + 0x7fffu + ((u >> 16) & 1u)) >> 16;
    return (u16)r;
}
__device__ inline float bflo(u32 u) { return __uint_as_float(u << 16); }
__device__ inline float bfhi(u32 u) { return __uint_as_float(u & 0xffff0000u); }

// ---------------- CSR build ----------------

__global__ void zero_counts_k(int* counts) {
    int i = blockIdx.x * 256 + threadIdx.x;
    if (i < N_NODES) counts[i] = 0;
}

__global__ void count_edges_k(const int* __restrict__ ei, int* __restrict__ counts) {
    int e = blockIdx.x * 256 + threadIdx.x;
    if (e < N_EDGES) atomicAdd(&counts[ei[N_EDGES + e]], 1);
}

__global__ void block_sums_k(const int* __restrict__ counts, int* __restrict__ partials) {
    __shared__ int sh[256];
    int t = threadIdx.x, b = blockIdx.x, i = b * 256 + t;
    sh[t] = (i < N_NODES) ? counts[i] : 0;
    __syncthreads();
    for (int off = 128; off > 0; off >>= 1) {
        if (t < off) sh[t] += sh[t + off];
        __syncthreads();
    }
    if (t == 0) partials[b] = sh[0];
}

__device__ inline int block_incl_scan(int v, int* sh, int t) {
    sh[t] = v;
    __syncthreads();
    for (int off = 1; off < 256; off <<= 1) {
        int add = (t >= off) ? sh[t - off] : 0;
        __syncthreads();
        sh[t] += add;
        __syncthreads();
    }
    int r = sh[t];
    __syncthreads();
    return r;
}

__global__ void scan_offsets_k(const int* __restrict__ partials, int* __restrict__ offsets) {
    __shared__ int sh[256];
    int t = threadIdx.x;
    int v = (t < NBLK) ? partials[t] : 0;
    int incl = block_incl_scan(v, sh, t);
    if (t < NBLK) offsets[t] = incl - v;   // exclusive
}

__global__ void scan_final_k(const int* __restrict__ counts, const int* __restrict__ offsets,
                             int* __restrict__ row_ptr, float* __restrict__ dinv) {
    __shared__ int sh[256];
    int t = threadIdx.x, b = blockIdx.x, i = b * 256 + t;
    int v = (i < N_NODES) ? counts[i] : 0;
    int incl = block_incl_scan(v, sh, t);
    if (i < N_NODES) {
        row_ptr[i + 1] = offsets[b] + incl;
        dinv[i] = 1.0f / sqrtf((float)(v + 1));
    }
    if (i == 0) row_ptr[0] = 0;
}

__global__ void init_cursor_k(const int* __restrict__ row_ptr, int* __restrict__ cursor) {
    int i = blockIdx.x * 256 + threadIdx.x;
    if (i < N_NODES) cursor[i] = row_ptr[i];
}

__global__ void fill_csr_k(const int* __restrict__ ei, int* __restrict__ cursor,
                           int* __restrict__ csr_src) {
    int e = blockIdx.x * 256 + threadIdx.x;
    if (e >= N_EDGES) return;
    int s = ei[e], d = ei[N_EDGES + e];
    int pos = atomicAdd(&cursor[d], 1);
    csr_src[pos] = s;
}

// ---------------- MFMA GEMM: out[NPAD,128](bf16) = in[NPAD,128] @ W[128,128](f32) ----
// INF32: input is f32 (cast to bf16 fragments in-register); else bf16.

template<int INF32>
__global__ __launch_bounds__(256) void gemm_mfma_k(const void* __restrict__ inv,
                                                   const float* __restrict__ W,
                                                   u16* __restrict__ out) {
    __shared__ u16 Wt[128 * 128];   // Wt[col][k] bf16, byte ^= (col&7)<<4
    int t = threadIdx.x;
    for (int i = t * 4; i < 128 * 128; i += 1024) {
        float4 w4 = *(const float4*)&W[i];
        int k = i >> 7, c0 = i & 127;
        u16 vals[4] = {bf16rn(w4.x), bf16rn(w4.y), bf16rn(w4.z), bf16rn(w4.w)};
        #pragma unroll
        for (int j = 0; j < 4; j++) {
            int col = c0 + j;
            int byte = (col << 8) | (((k << 1)) ^ ((col & 7) << 4));
            *(u16*)((char*)Wt + byte) = vals[j];
        }
    }
    __syncthreads();
    int w = t >> 6, lane = t & 63;
    int arow = lane & 15, kg = lane >> 4;
    int r0 = blockIdx.x * 128 + w * 32;

    bf16x8 a[2][4];
    #pragma unroll
    for (int rt = 0; rt < 2; rt++) {
        #pragma unroll
        for (int ks = 0; ks < 4; ks++) {
            if (INF32) {
                const float* rowp = (const float*)inv + (size_t)(r0 + rt * 16 + arow) * 128 + ks * 32 + kg * 8;
                float4 lo = *(const float4*)rowp;
                float4 hi = *(const float4*)(rowp + 4);
                bf16x8 v;
                v[0] = (short)bf16rn(lo.x); v[1] = (short)bf16rn(lo.y);
                v[2] = (short)bf16rn(lo.z); v[3] = (short)bf16rn(lo.w);
                v[4] = (short)bf16rn(hi.x); v[5] = (short)bf16rn(hi.y);
                v[6] = (short)bf16rn(hi.z); v[7] = (short)bf16rn(hi.w);
                a[rt][ks] = v;
            } else {
                a[rt][ks] = *(const bf16x8*)&((const u16*)inv)[(size_t)(r0 + rt * 16 + arow) * 128 + ks * 32 + kg * 8];
            }
        }
    }

    f32x4 acc[2][8];
    #pragma unroll
    for (int rt = 0; rt < 2; rt++)
        #pragma unroll
        for (int ct = 0; ct < 8; ct++) acc[rt][ct] = (f32x4){0.f, 0.f, 0.f, 0.f};

    #pragma unroll
    for (int ct = 0; ct < 8; ct++) {
        int col = ct * 16 + arow;
        int cbase = col << 8, swz = (col & 7) << 4;
        #pragma unroll
        for (int ks = 0; ks < 4; ks++) {
            int kb2 = (ks * 32 + kg * 8) << 1;
            bf16x8 b = *(const bf16x8*)((const char*)Wt + (cbase | (kb2 ^ swz)));
            acc[0][ct] = __builtin_amdgcn_mfma_f32_16x16x32_bf16(a[0][ks], b, acc[0][ct], 0, 0, 0);
            acc[1][ct] = __builtin_amdgcn_mfma_f32_16x16x32_bf16(a[1][ks], b, acc[1][ct], 0, 0, 0);
        }
    }
    #pragma unroll
    for (int rt = 0; rt < 2; rt++) {
        #pragma unroll
        for (int ct = 0; ct < 8; ct++) {
            int col = ct * 16 + arow;
            #pragma unroll
            for (int j = 0; j < 4; j++) {
                int row = r0 + rt * 16 + kg * 4 + j;
                if (row < N_NODES) out[(size_t)row * 128 + col] = bf16rn(acc[rt][ct][j]);
            }
        }
    }
}

// ---------------- aggregation: one wave per node, 4-deep pipelined CSR gather --------
// MODE 0: relu, bf16 out.  MODE 2: no relu, fused L2-normalize, f32 + bf16 out.

template<int MODE>
__global__ __launch_bounds__(256) void aggregate_k(const u16* __restrict__ hwb,
                                                   const int* __restrict__ row_ptr,
                                                   const int* __restrict__ csr_src,
                                                   const float* __restrict__ dinv,
                                                   const float* __restrict__ bias,
                                                   float* __restrict__ outf,
                                                   u16* __restrict__ outb) {
    int wid = (blockIdx.x * 256 + threadIdx.x) >> 6;
    int lane = threadIdx.x & 63;
    if (wid >= N_NODES) return;
    float di = dinv[wid];
    const u16* base = hwb + lane * 2;
    u32 u = *(const u32*)(base + (size_t)wid * 128);
    float ax = bflo(u) * di * di, ay = bfhi(u) * di * di;   // self loop
    int e = row_ptr[wid];
    int n = row_ptr[wid + 1] - e;
    int i = 0;
    for (; i + 4 <= n; i += 4) {
        int s0 = csr_src[e + i];
        int s1 = csr_src[e + i + 1];
        int s2 = csr_src[e + i + 2];
        int s3 = csr_src[e + i + 3];
        float w0 = dinv[s0] * di, w1 = dinv[s1] * di, w2 = dinv[s2] * di, w3 = dinv[s3] * di;
        u32 r0 = *(const u32*)(base + (size_t)s0 * 128);
        u32 r1 = *(const u32*)(base + (size_t)s1 * 128);
        u32 r2 = *(const u32*)(base + (size_t)s2 * 128);
        u32 r3 = *(const u32*)(base + (size_t)s3 * 128);
        ax += bflo(r0) * w0; ay += bfhi(r0) * w0;
        ax += bflo(r1) * w1; ay += bfhi(r1) * w1;
        ax += bflo(r2) * w2; ay += bfhi(r2) * w2;
        ax += bflo(r3) * w3; ay += bfhi(r3) * w3;
    }
    for (; i < n; ++i) {
        int s = csr_src[e + i];
        float w = dinv[s] * di;
        u32 r = *(const u32*)(base + (size_t)s * 128);
        ax += bflo(r) * w; ay += bfhi(r) * w;
    }
    float2 bb = *(const float2*)&bias[lane * 2];
    ax += bb.x;
    ay += bb.y;
    if (MODE == 0) {
        ax = fmaxf(ax, 0.f); ay = fmaxf(ay, 0.f);
        u32 o = (u32)bf16rn(ax) | ((u32)bf16rn(ay) << 16);
        *(u32*)&outb[(size_t)wid * 128 + lane * 2] = o;
    } else {
        // fused row L2 normalize
        float ss = ax * ax + ay * ay;
        for (int o = 32; o > 0; o >>= 1) ss += __shfl_xor(ss, o);
        float inv = 1.0f / sqrtf(ss);
        ax *= inv; ay *= inv;
        float2 r = {ax, ay};
        *(float2*)&outf[(size_t)wid * 128 + lane * 2] = r;
        u32 o = (u32)bf16rn(ax) | ((u32)bf16rn(ay) << 16);
        *(u32*)&outb[(size_t)wid * 128 + lane * 2] = o;
    }
}

// ---------------- prototype head: out_proto[100,7] log-probs (f32 path) ----------------

__global__ __launch_bounds__(128) void proto_head_k(const float* __restrict__ hn,
                                                    const int* __restrict__ prot,
                                                    const float* __restrict__ lw1,
                                                    const float* __restrict__ lb1,
                                                    const float* __restrict__ lw2,
                                                    const float* __restrict__ lb2,
                                                    float* __restrict__ out_proto) {
    __shared__ float a[128];
    __shared__ float hid[128];
    __shared__ float lg[7];
    __shared__ float lse_s;
    int p = blockIdx.x, t = threadIdx.x;
    int node = prot[p];
    a[t] = hn[(size_t)node * 128 + t];
    __syncthreads();
    float acc = lb1[t];
    for (int k = 0; k < 128; k++) acc += a[k] * lw1[k * 128 + t];
    hid[t] = fmaxf(acc, 0.f);
    __syncthreads();
    if (t < NC) {
        float l = lb2[t];
        for (int k = 0; k < 128; k++) l += hid[k] * lw2[k * NC + t];
        lg[t] = l;
    }
    __syncthreads();
    if (t == 0) {
        float m = lg[0];
        for (int c = 1; c < NC; c++) m = fmaxf(m, lg[c]);
        float s = 0.f;
        for (int c = 0; c < NC; c++) s += expf(lg[c] - m);
        lse_s = m + logf(s);
    }
    __syncthreads();
    if (t < NC) out_proto[p * NC + t] = lg[t] - lse_s;
}

// ---------------- fused MFMA rel-rep + classifier head ----------------

__global__ __launch_bounds__(256) void rel_out_k(const u16* __restrict__ hnb,
                                                 const int* __restrict__ prot,
                                                 const float* __restrict__ op,
                                                 float* __restrict__ x_rel,
                                                 float* __restrict__ out) {
    __shared__ u16 Asw[112 * 128];   // anchors[p][k] bf16, byte ^= (p&7)<<4 ; 28672 B
    __shared__ float OPl[112 * 9];   // out_proto padded [112][9] ; 4032 B
    int t = threadIdx.x;
    for (int i = t * 4; i < 112 * 128; i += 1024) {
        int p = i >> 7, k = i & 127;
        uint2 d = {0u, 0u};
        if (p < NP) d = *(const uint2*)&hnb[(size_t)prot[p] * 128 + k];
        int byte = (p << 8) | (((k << 1)) ^ ((p & 7) << 4));
        *(uint2*)((char*)Asw + byte) = d;
    }
    for (int i = t; i < 112 * 9; i += 256) {
        int p = i / 9, c = i % 9;
        OPl[i] = (p < NP && c < NC) ? op[p * NC + c] : 0.f;
    }
    __syncthreads();

    int w = t >> 6, lane = t & 63;
    int arow = lane & 15, kg = lane >> 4;
    int r0 = blockIdx.x * 128 + w * 32;

    bf16x8 a[2][4];
    #pragma unroll
    for (int rt = 0; rt < 2; rt++)
        #pragma unroll
        for (int ks = 0; ks < 4; ks++)
            a[rt][ks] = *(const bf16x8*)&hnb[(size_t)(r0 + rt * 16 + arow) * 128 + ks * 32 + kg * 8];

    f32x4 acc[2][7];
    #pragma unroll
    for (int rt = 0; rt < 2; rt++)
        #pragma unroll
        for (int ct = 0; ct < 7; ct++) acc[rt][ct] = (f32x4){0.f, 0.f, 0.f, 0.f};

    #pragma unroll
    for (int ct = 0; ct < 7; ct++) {
        int col = ct * 16 + arow;
        int cbase = col << 8, swz = (col & 7) << 4;
        #pragma unroll
        for (int ks = 0; ks < 4; ks++) {
            int kb2 = (ks * 32 + kg * 8) << 1;
            bf16x8 b = *(const bf16x8*)((const char*)Asw + (cbase | (kb2 ^ swz)));
            acc[0][ct] = __builtin_amdgcn_mfma_f32_16x16x32_bf16(a[0][ks], b, acc[0][ct], 0, 0, 0);
            acc[1][ct] = __builtin_amdgcn_mfma_f32_16x16x32_bf16(a[1][ks], b, acc[1][ct], 0, 0, 0);
        }
    }

    #pragma unroll
    for (int rt = 0; rt < 2; rt++) {
        #pragma unroll
        for (int j = 0; j < 4; j++) {
            int row = r0 + rt * 16 + kg * 4 + j;
            float lg[7] = {0.f, 0.f, 0.f, 0.f, 0.f, 0.f, 0.f};
            #pragma unroll
            for (int ct = 0; ct < 7; ct++) {
                int p = ct * 16 + arow;
                float xr = (acc[rt][ct][j] + 1.0f) * 0.5f;
                if (row < N_NODES && p < NP) x_rel[(size_t)row * NP + p] = xr;
                #pragma unroll
                for (int c = 0; c < NC; c++) lg[c] += xr * OPl[p * 9 + c];
            }
            #pragma unroll
            for (int m = 1; m < 16; m <<= 1) {
                #pragma unroll
                for (int c = 0; c < NC; c++) lg[c] += __shfl_xor(lg[c], m);
            }
            float mx = lg[0];
            #pragma unroll
            for (int c = 1; c < NC; c++) mx = fmaxf(mx, lg[c]);
            float s = 0.f;
            #pragma unroll
            for (int c = 0; c < NC; c++) s += expf(lg[c] - mx);
            float lse = mx + logf(s);
            if (arow == 0 && row < N_NODES) {
                #pragma unroll
                for (int c = 0; c < NC; c++) out[(size_t)row * NC + c] = lg[c] - lse;
            }
        }
    }
}

// ---------------- launch ----------------

extern "C" void kernel_launch(void* const* d_in, const int* in_sizes, int n_in,
                              void* d_out, int out_size, void* d_ws, size_t ws_size,
                              hipStream_t stream) {
    const float* x   = (const float*)d_in[0];
    const int*   ei  = (const int*)d_in[1];
    const int*   prot= (const int*)d_in[2];
    const float* W0  = (const float*)d_in[3];
    const float* b0  = (const float*)d_in[4];
    const float* W1  = (const float*)d_in[5];
    const float* b1  = (const float*)d_in[6];
    const float* W2  = (const float*)d_in[7];
    const float* b2  = (const float*)d_in[8];
    const float* lw1 = (const float*)d_in[9];
    const float* lb1 = (const float*)d_in[10];
    const float* lw2 = (const float*)d_in[11];
    const float* lb2 = (const float*)d_in[12];

    float* out       = (float*)d_out;                                      // [N,7]
    float* x_rel     = out + (size_t)N_NODES * NC;                         // [N,100]
    float* out_proto = out + (size_t)N_NODES * NC + (size_t)N_NODES * NP;  // [100,7]

    // workspace layout
    int* wi = (int*)d_ws;
    int* counts   = wi;             // 50000
    int* row_ptr  = wi + 50048;     // 50001
    int* cursor   = wi + 100096;    // 50000
    int* partials = wi + 150144;    // 256
    int* offsets  = wi + 150464;    // 256
    int* csr_src  = wi + 150784;    // 600000 -> ends 750784
    float* wf = (float*)d_ws;
    float* dinv = wf + 750848;      // 50000 -> 800848, round to 800896
    float* hnf  = wf + 800896;      // 6.4M f32 normalized h -> ends 7200896
    char* cb = (char*)d_ws;
    u16* xb  = (u16*)(cb + (size_t)7200896 * 4);                       // NPAD*128 bf16 = 12.8MB
    u16* hwb = (u16*)(cb + (size_t)7200896 * 4 + (size_t)NPAD * 256);  // 12.8MB
    u16* hb  = (u16*)(cb + (size_t)7200896 * 4 + (size_t)NPAD * 512);  // 12.8MB

    const int egrid = (N_EDGES + 255) / 256;  // 2344
    const int wgrid = (N_NODES * 64) / 256;   // 12500

    // CSR build + degrees
    hipLaunchKernelGGL(zero_counts_k, dim3(NBLK), dim3(256), 0, stream, counts);
    hipLaunchKernelGGL(count_edges_k, dim3(egrid), dim3(256), 0, stream, ei, counts);
    hipLaunchKernelGGL(block_sums_k, dim3(NBLK), dim3(256), 0, stream, counts, partials);
    hipLaunchKernelGGL(scan_offsets_k, dim3(1), dim3(256), 0, stream, partials, offsets);
    hipLaunchKernelGGL(scan_final_k, dim3(NBLK), dim3(256), 0, stream, counts, offsets, row_ptr, dinv);
    hipLaunchKernelGGL(init_cursor_k, dim3(NBLK), dim3(256), 0, stream, row_ptr, cursor);
    hipLaunchKernelGGL(fill_csr_k, dim3(egrid), dim3(256), 0, stream, ei, cursor, csr_src);

    // conv0 (f32 input fused cast)
    hipLaunchKernelGGL((gemm_mfma_k<1>), dim3(GBLK), dim3(256), 0, stream, (const void*)x, W0, hwb);
    hipLaunchKernelGGL((aggregate_k<0>), dim3(wgrid), dim3(256), 0, stream, hwb, row_ptr, csr_src, dinv, b0, (float*)nullptr, hb);
    // conv1
    hipLaunchKernelGGL((gemm_mfma_k<0>), dim3(GBLK), dim3(256), 0, stream, (const void*)hb, W1, hwb);
    hipLaunchKernelGGL((aggregate_k<0>), dim3(wgrid), dim3(256), 0, stream, hwb, row_ptr, csr_src, dinv, b1, (float*)nullptr, xb);
    // conv2 (no relu) + fused normalize -> hnf (f32) + hb (bf16)
    hipLaunchKernelGGL((gemm_mfma_k<0>), dim3(GBLK), dim3(256), 0, stream, (const void*)xb, W2, hwb);
    hipLaunchKernelGGL((aggregate_k<2>), dim3(wgrid), dim3(256), 0, stream, hwb, row_ptr, csr_src, dinv, b2, hnf, hb);

    // prototype head (f32 anchors) -> out_proto
    hipLaunchKernelGGL(proto_head_k, dim3(NP), dim3(128), 0, stream, hnf, prot, lw1, lb1, lw2, lb2, out_proto);

    // fused MFMA relative representation + classifier + log_softmax
    hipLaunchKernelGGL(rel_out_k, dim3(GBLK), dim3(256), 0, stream, hb, prot, out_proto, x_rel, out);
}

// Round 4
// 256.670 us; speedup vs baseline: 2.3020x; 1.0443x over previous
//
#include <hip/hip_runtime.h>
#include <math.h>

#define N_NODES 50000
#define N_EDGES 600000
#define NPAD 50048          // 391 * 128
#define D 128
#define NC 7
#define NP 100
#define NBLK 196            // ceil(N_NODES/256)
#define GBLK 391            // NPAD / 128

typedef unsigned short u16;
typedef unsigned int u32;
typedef __attribute__((ext_vector_type(8))) short bf16x8;
typedef __attribute__((ext_vector_type(4))) float f32x4;

__device__ inline u16 bf16rn(float f) {
    u32 u = __float_as_uint(f);
    u32 r = (u + 0x7fffu + ((u >> 16) & 1u)) >> 16;
    return (u16)r;
}
__device__ inline float bflo(u32 u) { return __uint_as_float(u << 16); }
__device__ inline float bfhi(u32 u) { return __uint_as_float(u & 0xffff0000u); }

// ---------------- CSR build ----------------

__global__ void zero_counts_k(int* counts) {
    int i = blockIdx.x * 256 + threadIdx.x;
    if (i < N_NODES) counts[i] = 0;
}

__global__ void count_edges_k(const int* __restrict__ ei, int* __restrict__ counts) {
    int e = blockIdx.x * 256 + threadIdx.x;
    if (e < N_EDGES) atomicAdd(&counts[ei[N_EDGES + e]], 1);
}

__global__ void block_sums_k(const int* __restrict__ counts, int* __restrict__ partials) {
    __shared__ int sh[256];
    int t = threadIdx.x, b = blockIdx.x, i = b * 256 + t;
    sh[t] = (i < N_NODES) ? counts[i] : 0;
    __syncthreads();
    for (int off = 128; off > 0; off >>= 1) {
        if (t < off) sh[t] += sh[t + off];
        __syncthreads();
    }
    if (t == 0) partials[b] = sh[0];
}

__device__ inline int block_incl_scan(int v, int* sh, int t) {
    sh[t] = v;
    __syncthreads();
    for (int off = 1; off < 256; off <<= 1) {
        int add = (t >= off) ? sh[t - off] : 0;
        __syncthreads();
        sh[t] += add;
        __syncthreads();
    }
    int r = sh[t];
    __syncthreads();
    return r;
}

__global__ void scan_offsets_k(const int* __restrict__ partials, int* __restrict__ offsets) {
    __shared__ int sh[256];
    int t = threadIdx.x;
    int v = (t < NBLK) ? partials[t] : 0;
    int incl = block_incl_scan(v, sh, t);
    if (t < NBLK) offsets[t] = incl - v;   // exclusive
}

__global__ void scan_final_k(const int* __restrict__ counts, const int* __restrict__ offsets,
                             int* __restrict__ row_ptr, float* __restrict__ dinv) {
    __shared__ int sh[256];
    int t = threadIdx.x, b = blockIdx.x, i = b * 256 + t;
    int v = (i < N_NODES) ? counts[i] : 0;
    int incl = block_incl_scan(v, sh, t);
    if (i < N_NODES) {
        row_ptr[i + 1] = offsets[b] + incl;
        dinv[i] = 1.0f / sqrtf((float)(v + 1));
    }
    if (i == 0) row_ptr[0] = 0;
}

__global__ void init_cursor_k(const int* __restrict__ row_ptr, int* __restrict__ cursor) {
    int i = blockIdx.x * 256 + threadIdx.x;
    if (i < N_NODES) cursor[i] = row_ptr[i];
}

__global__ void fill_csr_k(const int* __restrict__ ei, int* __restrict__ cursor,
                           int* __restrict__ csr_src) {
    int e = blockIdx.x * 256 + threadIdx.x;
    if (e >= N_EDGES) return;
    int s = ei[e], d = ei[N_EDGES + e];
    int pos = atomicAdd(&cursor[d], 1);
    csr_src[pos] = s;
}

// ---------------- prep: W[128][128] f32 -> fragment-ordered bf16 ----------------
// Wfrag[(ct*4+ks)*64 + lane] = 8 bf16: W[k][col], col=ct*16+(lane&15), k=ks*32+(lane>>4)*8+i

__global__ __launch_bounds__(256) void prep_w_k(const float* __restrict__ W,
                                                u16* __restrict__ Wfrag) {
    int t = threadIdx.x;
    #pragma unroll
    for (int w = 0; w < 8; w++) {
        int slot = t + w * 256;            // 0..2047
        int lane = slot & 63, ks = (slot >> 6) & 3, ct = slot >> 8;
        int arow = lane & 15, kg = lane >> 4;
        int col = ct * 16 + arow;
        bf16x8 v;
        #pragma unroll
        for (int i = 0; i < 8; i++) {
            int k = ks * 32 + kg * 8 + i;
            v[i] = (short)bf16rn(W[k * 128 + col]);
        }
        *(bf16x8*)&Wfrag[slot * 8] = v;
    }
}

// ---------------- prep: anchor fragments + folded classifier matrix ----------------
// AFrag: 7 ct-tiles of anchors (bf16, zero-padded past 100).
// MhG[128*8+8]: Mh[k][c] = 0.5*sum_p anchors_f32[p][k]*OP[p][c]; MhG[1024+c] = 0.5*colsum(OP)[c]

__global__ __launch_bounds__(256) void prep_anchor_k(const u16* __restrict__ hnb,
                                                     const float* __restrict__ hnf,
                                                     const int* __restrict__ prot,
                                                     const float* __restrict__ op,
                                                     u16* __restrict__ AFrag,
                                                     float* __restrict__ MhG) {
    int t = threadIdx.x;
    for (int s = t; s < 7 * 4 * 64; s += 256) {
        int lane = s & 63, ks = (s >> 6) & 3, ct = s >> 8;
        int arow = lane & 15, kg = lane >> 4;
        int col = ct * 16 + arow;
        bf16x8 v = {0, 0, 0, 0, 0, 0, 0, 0};
        if (col < NP) {
            int node = prot[col];
            v = *(const bf16x8*)&hnb[(size_t)node * 128 + ks * 32 + kg * 8];
        }
        *(bf16x8*)&AFrag[s * 8] = v;
    }
    if (t < 128) {
        float m[7] = {0.f, 0.f, 0.f, 0.f, 0.f, 0.f, 0.f};
        for (int p = 0; p < NP; p++) {
            float an = hnf[(size_t)prot[p] * 128 + t];
            #pragma unroll
            for (int c = 0; c < NC; c++) m[c] += an * op[p * NC + c];
        }
        #pragma unroll
        for (int c = 0; c < NC; c++) MhG[t * 8 + c] = 0.5f * m[c];
        MhG[t * 8 + 7] = 0.f;
    } else if (t < 128 + NC) {
        int c = t - 128;
        float s = 0.f;
        for (int p = 0; p < NP; p++) s += op[p * NC + c];
        MhG[1024 + c] = 0.5f * s;
    }
}

// ---------------- MFMA GEMM: out[N,128](bf16) = in @ W, B from fragment-ordered global --

template<int INF32>
__global__ __launch_bounds__(256) void gemm_mfma_k(const void* __restrict__ inv,
                                                   const u16* __restrict__ Wfrag,
                                                   u16* __restrict__ out) {
    int t = threadIdx.x;
    int w = t >> 6, lane = t & 63;
    int arow = lane & 15, kg = lane >> 4;
    int r0 = blockIdx.x * 128 + w * 32;

    bf16x8 a[2][4];
    #pragma unroll
    for (int rt = 0; rt < 2; rt++) {
        int row = r0 + rt * 16 + arow;
        if (row > N_NODES - 1) row = N_NODES - 1;
        #pragma unroll
        for (int ks = 0; ks < 4; ks++) {
            if (INF32) {
                const float* rowp = (const float*)inv + (size_t)row * 128 + ks * 32 + kg * 8;
                float4 lo = *(const float4*)rowp;
                float4 hi = *(const float4*)(rowp + 4);
                bf16x8 v;
                v[0] = (short)bf16rn(lo.x); v[1] = (short)bf16rn(lo.y);
                v[2] = (short)bf16rn(lo.z); v[3] = (short)bf16rn(lo.w);
                v[4] = (short)bf16rn(hi.x); v[5] = (short)bf16rn(hi.y);
                v[6] = (short)bf16rn(hi.z); v[7] = (short)bf16rn(hi.w);
                a[rt][ks] = v;
            } else {
                a[rt][ks] = *(const bf16x8*)&((const u16*)inv)[(size_t)row * 128 + ks * 32 + kg * 8];
            }
        }
    }

    f32x4 acc[2][8];
    #pragma unroll
    for (int rt = 0; rt < 2; rt++)
        #pragma unroll
        for (int ct = 0; ct < 8; ct++) acc[rt][ct] = (f32x4){0.f, 0.f, 0.f, 0.f};

    #pragma unroll
    for (int ct = 0; ct < 8; ct++) {
        bf16x8 b[4];
        #pragma unroll
        for (int ks = 0; ks < 4; ks++)
            b[ks] = *(const bf16x8*)&Wfrag[((ct * 4 + ks) * 64 + lane) * 8];
        #pragma unroll
        for (int ks = 0; ks < 4; ks++) {
            acc[0][ct] = __builtin_amdgcn_mfma_f32_16x16x32_bf16(a[0][ks], b[ks], acc[0][ct], 0, 0, 0);
            acc[1][ct] = __builtin_amdgcn_mfma_f32_16x16x32_bf16(a[1][ks], b[ks], acc[1][ct], 0, 0, 0);
        }
    }
    #pragma unroll
    for (int rt = 0; rt < 2; rt++) {
        #pragma unroll
        for (int ct = 0; ct < 8; ct++) {
            int col = ct * 16 + arow;
            #pragma unroll
            for (int j = 0; j < 4; j++) {
                int row = r0 + rt * 16 + kg * 4 + j;
                if (row < N_NODES) out[(size_t)row * 128 + col] = bf16rn(acc[rt][ct][j]);
            }
        }
    }
}

// ---------------- aggregation: one wave per node, 8-deep pipelined CSR gather --------
// MODE 0: relu, bf16 out.  MODE 2: no relu, fused L2-normalize, f32 + bf16 out.

template<int MODE>
__global__ __launch_bounds__(256) void aggregate_k(const u16* __restrict__ hwb,
                                                   const int* __restrict__ row_ptr,
                                                   const int* __restrict__ csr_src,
                                                   const float* __restrict__ dinv,
                                                   const float* __restrict__ bias,
                                                   float* __restrict__ outf,
                                                   u16* __restrict__ outb) {
    int wid = (blockIdx.x * 256 + threadIdx.x) >> 6;
    int lane = threadIdx.x & 63;
    if (wid >= N_NODES) return;
    float di = dinv[wid];
    const u16* base = hwb + lane * 2;
    u32 u = *(const u32*)(base + (size_t)wid * 128);
    float ax = bflo(u) * di * di, ay = bfhi(u) * di * di;   // self loop
    int e = row_ptr[wid];
    int n = row_ptr[wid + 1] - e;
    int i = 0;
    for (; i + 8 <= n; i += 8) {
        int s0 = csr_src[e + i + 0], s1 = csr_src[e + i + 1];
        int s2 = csr_src[e + i + 2], s3 = csr_src[e + i + 3];
        int s4 = csr_src[e + i + 4], s5 = csr_src[e + i + 5];
        int s6 = csr_src[e + i + 6], s7 = csr_src[e + i + 7];
        float w0 = dinv[s0] * di, w1 = dinv[s1] * di, w2 = dinv[s2] * di, w3 = dinv[s3] * di;
        float w4 = dinv[s4] * di, w5 = dinv[s5] * di, w6 = dinv[s6] * di, w7 = dinv[s7] * di;
        u32 r0 = *(const u32*)(base + (size_t)s0 * 128);
        u32 r1 = *(const u32*)(base + (size_t)s1 * 128);
        u32 r2 = *(const u32*)(base + (size_t)s2 * 128);
        u32 r3 = *(const u32*)(base + (size_t)s3 * 128);
        u32 r4 = *(const u32*)(base + (size_t)s4 * 128);
        u32 r5 = *(const u32*)(base + (size_t)s5 * 128);
        u32 r6 = *(const u32*)(base + (size_t)s6 * 128);
        u32 r7 = *(const u32*)(base + (size_t)s7 * 128);
        ax += bflo(r0) * w0; ay += bfhi(r0) * w0;
        ax += bflo(r1) * w1; ay += bfhi(r1) * w1;
        ax += bflo(r2) * w2; ay += bfhi(r2) * w2;
        ax += bflo(r3) * w3; ay += bfhi(r3) * w3;
        ax += bflo(r4) * w4; ay += bfhi(r4) * w4;
        ax += bflo(r5) * w5; ay += bfhi(r5) * w5;
        ax += bflo(r6) * w6; ay += bfhi(r6) * w6;
        ax += bflo(r7) * w7; ay += bfhi(r7) * w7;
    }
    for (; i + 4 <= n; i += 4) {
        int s0 = csr_src[e + i + 0], s1 = csr_src[e + i + 1];
        int s2 = csr_src[e + i + 2], s3 = csr_src[e + i + 3];
        float w0 = dinv[s0] * di, w1 = dinv[s1] * di, w2 = dinv[s2] * di, w3 = dinv[s3] * di;
        u32 r0 = *(const u32*)(base + (size_t)s0 * 128);
        u32 r1 = *(const u32*)(base + (size_t)s1 * 128);
        u32 r2 = *(const u32*)(base + (size_t)s2 * 128);
        u32 r3 = *(const u32*)(base + (size_t)s3 * 128);
        ax += bflo(r0) * w0; ay += bfhi(r0) * w0;
        ax += bflo(r1) * w1; ay += bfhi(r1) * w1;
        ax += bflo(r2) * w2; ay += bfhi(r2) * w2;
        ax += bflo(r3) * w3; ay += bfhi(r3) * w3;
    }
    for (; i < n; ++i) {
        int s = csr_src[e + i];
        float w = dinv[s] * di;
        u32 r = *(const u32*)(base + (size_t)s * 128);
        ax += bflo(r) * w; ay += bfhi(r) * w;
    }
    float2 bb = *(const float2*)&bias[lane * 2];
    ax += bb.x;
    ay += bb.y;
    if (MODE == 0) {
        ax = fmaxf(ax, 0.f); ay = fmaxf(ay, 0.f);
        u32 o = (u32)bf16rn(ax) | ((u32)bf16rn(ay) << 16);
        *(u32*)&outb[(size_t)wid * 128 + lane * 2] = o;
    } else {
        float ss = ax * ax + ay * ay;
        for (int o = 32; o > 0; o >>= 1) ss += __shfl_xor(ss, o);
        float inv = 1.0f / sqrtf(ss);
        ax *= inv; ay *= inv;
        float2 r = {ax, ay};
        *(float2*)&outf[(size_t)wid * 128 + lane * 2] = r;
        u32 o = (u32)bf16rn(ax) | ((u32)bf16rn(ay) << 16);
        *(u32*)&outb[(size_t)wid * 128 + lane * 2] = o;
    }
}

// ---------------- prototype head: out_proto[100,7] log-probs (f32 path) ----------------

__global__ __launch_bounds__(128) void proto_head_k(const float* __restrict__ hn,
                                                    const int* __restrict__ prot,
                                                    const float* __restrict__ lw1,
                                                    const float* __restrict__ lb1,
                                                    const float* __restrict__ lw2,
                                                    const float* __restrict__ lb2,
                                                    float* __restrict__ out_proto) {
    __shared__ float a[128];
    __shared__ float hid[128];
    __shared__ float lg[7];
    __shared__ float lse_s;
    int p = blockIdx.x, t = threadIdx.x;
    int node = prot[p];
    a[t] = hn[(size_t)node * 128 + t];
    __syncthreads();
    float acc = lb1[t];
    for (int k = 0; k < 128; k++) acc += a[k] * lw1[k * 128 + t];
    hid[t] = fmaxf(acc, 0.f);
    __syncthreads();
    if (t < NC) {
        float l = lb2[t];
        for (int k = 0; k < 128; k++) l += hid[k] * lw2[k * NC + t];
        lg[t] = l;
    }
    __syncthreads();
    if (t == 0) {
        float m = lg[0];
        for (int c = 1; c < NC; c++) m = fmaxf(m, lg[c]);
        float s = 0.f;
        for (int c = 0; c < NC; c++) s += expf(lg[c] - m);
        lse_s = m + logf(s);
    }
    __syncthreads();
    if (t < NC) out_proto[p * NC + t] = lg[t] - lse_s;
}

// ---------------- fused MFMA rel-rep + folded classifier + log_softmax ----------------

__global__ __launch_bounds__(256) void rel_out_k(const u16* __restrict__ hnb,
                                                 const u16* __restrict__ AFrag,
                                                 const float* __restrict__ MhG,
                                                 float* __restrict__ x_rel,
                                                 float* __restrict__ out) {
    __shared__ float Mh[128 * 8];
    __shared__ float shc[8];
    int t = threadIdx.x;
    for (int i = t; i < 128 * 8; i += 256) Mh[i] = MhG[i];
    if (t < 8) shc[t] = (t < NC) ? MhG[1024 + t] : 0.f;
    __syncthreads();

    int w = t >> 6, lane = t & 63;
    int arow = lane & 15, kg = lane >> 4;
    int r0 = blockIdx.x * 128 + w * 32;

    bf16x8 a[2][4];
    #pragma unroll
    for (int rt = 0; rt < 2; rt++) {
        int row = r0 + rt * 16 + arow;
        if (row > N_NODES - 1) row = N_NODES - 1;
        #pragma unroll
        for (int ks = 0; ks < 4; ks++)
            a[rt][ks] = *(const bf16x8*)&hnb[(size_t)row * 128 + ks * 32 + kg * 8];
    }

    f32x4 acc[2][7];
    #pragma unroll
    for (int rt = 0; rt < 2; rt++)
        #pragma unroll
        for (int ct = 0; ct < 7; ct++) acc[rt][ct] = (f32x4){0.f, 0.f, 0.f, 0.f};

    #pragma unroll
    for (int ct = 0; ct < 7; ct++) {
        bf16x8 b[4];
        #pragma unroll
        for (int ks = 0; ks < 4; ks++)
            b[ks] = *(const bf16x8*)&AFrag[((ct * 4 + ks) * 64 + lane) * 8];
        #pragma unroll
        for (int ks = 0; ks < 4; ks++) {
            acc[0][ct] = __builtin_amdgcn_mfma_f32_16x16x32_bf16(a[0][ks], b[ks], acc[0][ct], 0, 0, 0);
            acc[1][ct] = __builtin_amdgcn_mfma_f32_16x16x32_bf16(a[1][ks], b[ks], acc[1][ct], 0, 0, 0);
        }
    }

    // x_rel stores (C layout: col=arow-tile, row=kg*4+j)
    #pragma unroll
    for (int rt = 0; rt < 2; rt++) {
        #pragma unroll
        for (int ct = 0; ct < 7; ct++) {
            int p = ct * 16 + arow;
            if (p < NP) {
                #pragma unroll
                for (int j = 0; j < 4; j++) {
                    int row = r0 + rt * 16 + kg * 4 + j;
                    if (row < N_NODES) x_rel[(size_t)row * NP + p] = (acc[rt][ct][j] + 1.0f) * 0.5f;
                }
            }
        }
    }

    // lg = hn @ Mh (per-lane partial over its 32 k-values, reduce over kg) + shc
    #pragma unroll
    for (int rt = 0; rt < 2; rt++) {
        int row = r0 + rt * 16 + arow;
        float lg[7] = {0.f, 0.f, 0.f, 0.f, 0.f, 0.f, 0.f};
        #pragma unroll
        for (int ks = 0; ks < 4; ks++) {
            const u32* au = (const u32*)&a[rt][ks];
            #pragma unroll
            for (int i2 = 0; i2 < 4; i2++) {
                float lo = bflo(au[i2]), hi = bfhi(au[i2]);
                int k = ks * 32 + kg * 8 + i2 * 2;
                #pragma unroll
                for (int c = 0; c < NC; c++)
                    lg[c] += lo * Mh[k * 8 + c] + hi * Mh[(k + 1) * 8 + c];
            }
        }
        #pragma unroll
        for (int c = 0; c < NC; c++) {
            lg[c] += __shfl_xor(lg[c], 16);
            lg[c] += __shfl_xor(lg[c], 32);
            lg[c] += shc[c];
        }
        float mx = lg[0];
        #pragma unroll
        for (int c = 1; c < NC; c++) mx = fmaxf(mx, lg[c]);
        float s = 0.f;
        #pragma unroll
        for (int c = 0; c < NC; c++) s += expf(lg[c] - mx);
        float lse = mx + logf(s);
        if (kg == 0 && row < N_NODES) {
            #pragma unroll
            for (int c = 0; c < NC; c++) out[(size_t)row * NC + c] = lg[c] - lse;
        }
    }
}

// ---------------- launch ----------------

extern "C" void kernel_launch(void* const* d_in, const int* in_sizes, int n_in,
                              void* d_out, int out_size, void* d_ws, size_t ws_size,
                              hipStream_t stream) {
    const float* x   = (const float*)d_in[0];
    const int*   ei  = (const int*)d_in[1];
    const int*   prot= (const int*)d_in[2];
    const float* W0  = (const float*)d_in[3];
    const float* b0  = (const float*)d_in[4];
    const float* W1  = (const float*)d_in[5];
    const float* b1  = (const float*)d_in[6];
    const float* W2  = (const float*)d_in[7];
    const float* b2  = (const float*)d_in[8];
    const float* lw1 = (const float*)d_in[9];
    const float* lb1 = (const float*)d_in[10];
    const float* lw2 = (const float*)d_in[11];
    const float* lb2 = (const float*)d_in[12];

    float* out       = (float*)d_out;                                      // [N,7]
    float* x_rel     = out + (size_t)N_NODES * NC;                         // [N,100]
    float* out_proto = out + (size_t)N_NODES * NC + (size_t)N_NODES * NP;  // [100,7]

    // workspace layout
    int* wi = (int*)d_ws;
    int* counts   = wi;             // 50000
    int* row_ptr  = wi + 50048;     // 50001
    int* cursor   = wi + 100096;    // 50000
    int* partials = wi + 150144;    // 256
    int* offsets  = wi + 150464;    // 256
    int* csr_src  = wi + 150784;    // 600000 -> ends 750784
    float* wf = (float*)d_ws;
    float* dinv = wf + 750848;      // 50000 -> 800848, pad to 800896
    float* hnf  = wf + 800896;      // NPAD*128 = 6406144 -> ends 7207040
    float* MhG  = wf + 7207040;     // 1032 -> pad to 7208192
    char* cb = (char*)d_ws;
    u16* xb    = (u16*)(cb + (size_t)7208192 * 4);                        // 12812288 B
    u16* hwb   = (u16*)(cb + (size_t)7208192 * 4 + (size_t)NPAD * 256);   // 12812288 B
    u16* hb    = (u16*)(cb + (size_t)7208192 * 4 + (size_t)NPAD * 512);   // 12812288 B
    u16* Wf0   = (u16*)(cb + (size_t)7208192 * 4 + (size_t)NPAD * 768);            // 32768 B
    u16* Wf1   = (u16*)(cb + (size_t)7208192 * 4 + (size_t)NPAD * 768 + 32768);    // 32768 B
    u16* Wf2   = (u16*)(cb + (size_t)7208192 * 4 + (size_t)NPAD * 768 + 65536);    // 32768 B
    u16* AFrag = (u16*)(cb + (size_t)7208192 * 4 + (size_t)NPAD * 768 + 98304);    // 28672 B

    const int egrid = (N_EDGES + 255) / 256;  // 2344
    const int wgrid = (N_NODES * 64) / 256;   // 12500

    // CSR build + degrees
    hipLaunchKernelGGL(zero_counts_k, dim3(NBLK), dim3(256), 0, stream, counts);
    hipLaunchKernelGGL(count_edges_k, dim3(egrid), dim3(256), 0, stream, ei, counts);
    hipLaunchKernelGGL(block_sums_k, dim3(NBLK), dim3(256), 0, stream, counts, partials);
    hipLaunchKernelGGL(scan_offsets_k, dim3(1), dim3(256), 0, stream, partials, offsets);
    hipLaunchKernelGGL(scan_final_k, dim3(NBLK), dim3(256), 0, stream, counts, offsets, row_ptr, dinv);
    hipLaunchKernelGGL(init_cursor_k, dim3(NBLK), dim3(256), 0, stream, row_ptr, cursor);
    hipLaunchKernelGGL(fill_csr_k, dim3(egrid), dim3(256), 0, stream, ei, cursor, csr_src);

    // W fragment prep
    hipLaunchKernelGGL(prep_w_k, dim3(1), dim3(256), 0, stream, W0, Wf0);
    hipLaunchKernelGGL(prep_w_k, dim3(1), dim3(256), 0, stream, W1, Wf1);
    hipLaunchKernelGGL(prep_w_k, dim3(1), dim3(256), 0, stream, W2, Wf2);

    // conv0 (f32 input, fused cast)
    hipLaunchKernelGGL((gemm_mfma_k<1>), dim3(GBLK), dim3(256), 0, stream, (const void*)x, Wf0, hwb);
    hipLaunchKernelGGL((aggregate_k<0>), dim3(wgrid), dim3(256), 0, stream, hwb, row_ptr, csr_src, dinv, b0, (float*)nullptr, hb);
    // conv1
    hipLaunchKernelGGL((gemm_mfma_k<0>), dim3(GBLK), dim3(256), 0, stream, (const void*)hb, Wf1, hwb);
    hipLaunchKernelGGL((aggregate_k<0>), dim3(wgrid), dim3(256), 0, stream, hwb, row_ptr, csr_src, dinv, b1, (float*)nullptr, xb);
    // conv2 (no relu) + fused normalize -> hnf (f32) + hb (bf16)
    hipLaunchKernelGGL((gemm_mfma_k<0>), dim3(GBLK), dim3(256), 0, stream, (const void*)xb, Wf2, hwb);
    hipLaunchKernelGGL((aggregate_k<2>), dim3(wgrid), dim3(256), 0, stream, hwb, row_ptr, csr_src, dinv, b2, hnf, hb);

    // prototype head -> out_proto
    hipLaunchKernelGGL(proto_head_k, dim3(NP), dim3(128), 0, stream, hnf, prot, lw1, lb1, lw2, lb2, out_proto);

    // anchor fragments + folded classifier matrix
    hipLaunchKernelGGL(prep_anchor_k, dim3(1), dim3(256), 0, stream, hb, hnf, prot, out_proto, AFrag, MhG);

    // fused MFMA relative representation + classifier + log_softmax
    hipLaunchKernelGGL(rel_out_k, dim3(GBLK), dim3(256), 0, stream, hb, AFrag, MhG, x_rel, out);
}